// Round 12
// baseline (378.351 us; speedup 1.0000x reference)
//
#include <hip/hip_runtime.h>
#include <hip/hip_bf16.h>
#include <stdint.h>

// ---------------------------------------------------------------------------
// LinearFLHGS: per-group(64) symmetric int4 quant-dequant of x and w, then
// C = x_dq @ w_dq^T.  Round 12: 8-phase 256x256 bf16 GEMM with CROSS-PHASE
// read pipelining.  Reads issued in phase p feed phase p+1's MFMAs; post-
// barrier waits are counted lgkmcnt (4/8/0/none), so the LDS pipe drains
// UNDER the MFMA clusters instead of serializing before them (the 40%-
// MfmaUtil invariant of rounds 1-4/11).  Read balance 4/8/4/8 per phase.
// Ledger: stage(t+2->cb) at ph4 after ph3-MID lgkm0 (drains last cb read,
// aHi) + ph3-END barrier; nb readable after ph3 vmcnt(0) (3-phase-old loads,
// ~free) + MID barrier; SB0 after every wait (rule 18); tail by guards.
// Swizzle (0 conflicts), epilogue, quant proven in rounds 1-11.
// ---------------------------------------------------------------------------

typedef __bf16 bf16x8 __attribute__((ext_vector_type(8)));
typedef float f32x4 __attribute__((ext_vector_type(4)));

static __device__ __forceinline__ uint16_t f32_to_bf16_rne(float f) {
    uint32_t u = __float_as_uint(f);
    uint32_t r = (u + 0x7fffu + ((u >> 16) & 1u)) >> 16;
    return (uint16_t)r;
}

__global__ void quant_kernel(const float* __restrict__ in,
                             uint16_t* __restrict__ out, int total4) {
    int nthreads = gridDim.x * blockDim.x;
    int t = blockIdx.x * blockDim.x + threadIdx.x;
    for (int i = t; i < total4; i += nthreads) {
        float4 v = ((const float4*)in)[i];
        float amax = fmaxf(fmaxf(fabsf(v.x), fabsf(v.y)),
                           fmaxf(fabsf(v.z), fabsf(v.w)));
        #pragma unroll
        for (int m = 1; m <= 8; m <<= 1)
            amax = fmaxf(amax, __shfl_xor(amax, m, 64));
        float s = fmaxf(amax / 7.0f, 1e-8f);
        float q0 = fminf(fmaxf(rintf(v.x / s), -8.0f), 7.0f);
        float q1 = fminf(fmaxf(rintf(v.y / s), -8.0f), 7.0f);
        float q2 = fminf(fmaxf(rintf(v.z / s), -8.0f), 7.0f);
        float q3 = fminf(fmaxf(rintf(v.w / s), -8.0f), 7.0f);
        ushort4 o;
        o.x = f32_to_bf16_rne(q0 * s);
        o.y = f32_to_bf16_rne(q1 * s);
        o.z = f32_to_bf16_rne(q2 * s);
        o.w = f32_to_bf16_rne(q3 * s);
        ((ushort4*)out)[i] = o;
    }
}

#define BM 256
#define BN 256
#define BK 64

#define FENCE() asm volatile("" ::: "memory")
#define SB0()   __builtin_amdgcn_sched_barrier(0)

__global__ __launch_bounds__(512, 2) void gemm_kernel(
        const uint16_t* __restrict__ A, const uint16_t* __restrict__ B,
        float* __restrict__ C, int M, int N, int K) {
    __shared__ uint16_t As[2][2][128 * 64];   // [buf][half] 16 KB each
    __shared__ uint16_t Bs[2][2][128 * 64];

    const int NTt = K >> 6;   // 64 K-tiles

    int nwg = gridDim.x;
    int bid = blockIdx.x;
    int swz = bid;
    if ((nwg & 7) == 0) {
        int cpx = nwg >> 3;
        swz = (bid & 7) * cpx + (bid >> 3);
    }
    int nbn = N / BN;
    int bm = swz / nbn, bn = swz % nbn;

    int tid = threadIdx.x;
    int lane = tid & 63;
    int wid = tid >> 6;       // 0..7
    int wm = wid >> 2;        // 0..1 : 128-row band of A
    int wn = wid & 3;         // 0..3 : 64-col band of B

    const int rowA0 = bm * BM;
    const int colB0 = bn * BN;

    int srow = lane >> 3;
    int scol = ((lane & 7) ^ (lane >> 3)) << 3;

    int rl = lane & 15;
    int cg = lane >> 4;
    int coff[2];
    coff[0] = ((0 + cg) ^ (rl & 7)) << 3;
    coff[1] = ((4 + cg) ^ (rl & 7)) << 3;

    const int bhalf = wn >> 1;
    const int brow0 = (wn & 1) * 64;

    f32x4 acc[8][4] = {};
    bf16x8 aLo[4][2], aHi[4][2], bLo[2][2], bHi[2][2];

    auto stageA = [&](int buf, int half, int t) {
        #pragma unroll
        for (int j = 0; j < 2; ++j) {
            int rowin = wid * 16 + j * 8;
            const uint16_t* g = A + (size_t)(rowA0 + half * 128 + rowin + srow) * K
                                  + t * 64 + scol;
            uint16_t* l = &As[buf][half][rowin * 64];
            __builtin_amdgcn_global_load_lds(
                (const __attribute__((address_space(1))) void*)g,
                (__attribute__((address_space(3))) void*)l, 16, 0, 0);
        }
    };
    auto stageB = [&](int buf, int half, int t) {
        #pragma unroll
        for (int j = 0; j < 2; ++j) {
            int rowin = wid * 16 + j * 8;
            const uint16_t* g = B + (size_t)(colB0 + half * 128 + rowin + srow) * K
                                  + t * 64 + scol;
            uint16_t* l = &Bs[buf][half][rowin * 64];
            __builtin_amdgcn_global_load_lds(
                (const __attribute__((address_space(1))) void*)g,
                (__attribute__((address_space(3))) void*)l, 16, 0, 0);
        }
    };

    auto readA = [&](bf16x8 (&dst)[4][2], int lo, int buf) {
        #pragma unroll
        for (int mi = 0; mi < 4; ++mi)
            #pragma unroll
            for (int ks = 0; ks < 2; ++ks)
                dst[mi][ks] = *(const bf16x8*)&As[buf][wm][((lo + mi) * 16 + rl) * 64 + coff[ks]];
    };
    auto readB = [&](bf16x8 (&dst)[2][2], int lo, int buf) {
        #pragma unroll
        for (int ni = 0; ni < 2; ++ni)
            #pragma unroll
            for (int ks = 0; ks < 2; ++ks)
                dst[ni][ks] = *(const bf16x8*)&Bs[buf][bhalf][(brow0 + (lo + ni) * 16 + rl) * 64 + coff[ks]];
    };

    auto quadQ = [&](const bf16x8 (&af)[4][2], const bf16x8 (&bf)[2][2],
                     int mo, int no) {
        #pragma unroll
        for (int mi = 0; mi < 4; ++mi)
            #pragma unroll
            for (int ni = 0; ni < 2; ++ni)
                #pragma unroll
                for (int ks = 0; ks < 2; ++ks)
                    acc[mo + mi][no + ni] = __builtin_amdgcn_mfma_f32_16x16x32_bf16(
                        af[mi][ks], bf[ni][ks], acc[mo + mi][no + ni], 0, 0, 0);
    };

    // ---- prologue: stage T0,T1 fully; land T0; pre-read aLo/bLo of T0 ----
    stageA(0, 0, 0); stageA(0, 1, 0); stageB(0, 0, 0); stageB(0, 1, 0);
    stageA(1, 0, 1); stageA(1, 1, 1); stageB(1, 0, 1); stageB(1, 1, 1);
    asm volatile("s_waitcnt vmcnt(8)" ::: "memory");
    FENCE(); __builtin_amdgcn_s_barrier(); FENCE();
    readA(aLo, 0, 0); readB(bLo, 0, 0);       // 12 reads, drain under ph1

    for (int t = 0; t < NTt; ++t) {
        int cb = t & 1, nb = cb ^ 1;

        // ---- ph1: issue bHi(t)[4]; Q1 = aLo x bLo (read last ph3/ph4) ----
        readB(bHi, 2, cb);
        FENCE(); __builtin_amdgcn_s_barrier();
        asm volatile("s_waitcnt lgkmcnt(4)" ::: "memory");  // aLo,bLo done
        SB0(); __builtin_amdgcn_s_setprio(1);
        quadQ(aLo, bLo, 0, 0);
        __builtin_amdgcn_s_setprio(0);
        FENCE(); __builtin_amdgcn_s_barrier(); FENCE();

        // ---- ph2: issue aHi(t)[8]; Q2 = aLo x bHi ----
        readA(aHi, 4, cb);
        FENCE(); __builtin_amdgcn_s_barrier();
        asm volatile("s_waitcnt lgkmcnt(8)" ::: "memory");  // bHi done
        SB0(); __builtin_amdgcn_s_setprio(1);
        quadQ(aLo, bHi, 0, 2);
        __builtin_amdgcn_s_setprio(0);
        FENCE(); __builtin_amdgcn_s_barrier(); FENCE();

        // ---- ph3: vmcnt(0) on 3-phase-old stages (t+1 landed); Q3; then
        //           issue bLo(t+1)[4] from nb (visible after MID barrier) ----
        asm volatile("s_waitcnt vmcnt(0)" ::: "memory");
        FENCE(); __builtin_amdgcn_s_barrier();
        asm volatile("s_waitcnt lgkmcnt(0)" ::: "memory");  // aHi done (seal cb)
        SB0(); __builtin_amdgcn_s_setprio(1);
        quadQ(aHi, bLo, 4, 0);
        __builtin_amdgcn_s_setprio(0);
        if (t + 1 < NTt) readB(bLo, 0, nb);                 // after Q3 (WAR)
        FENCE(); __builtin_amdgcn_s_barrier(); FENCE();     // seal of cb reads

        // ---- ph4: stage t+2 -> cb (seal done ph3); issue aLo(t+1)[8];
        //           Q4 = aHi x bHi (both already waited) ----
        if (t + 2 < NTt) {
            stageA(cb, 0, t + 2); stageA(cb, 1, t + 2);
            stageB(cb, 0, t + 2); stageB(cb, 1, t + 2);
        }
        if (t + 1 < NTt) readA(aLo, 0, nb);
        FENCE(); __builtin_amdgcn_s_barrier();
        SB0(); __builtin_amdgcn_s_setprio(1);
        quadQ(aHi, bHi, 4, 2);
        __builtin_amdgcn_s_setprio(0);
        FENCE(); __builtin_amdgcn_s_barrier(); FENCE();
    }

    // ---- epilogue: D map col = lane&15, row = (lane>>4)*4 + reg ----
    int cl = lane & 15;
    int rq = (lane >> 4) * 4;
    #pragma unroll
    for (int mi = 0; mi < 8; ++mi) {
        #pragma unroll
        for (int ni = 0; ni < 4; ++ni) {
            int row = rowA0 + wm * 128 + mi * 16 + rq;
            int col = colB0 + wn * 64 + ni * 16 + cl;
            float* cp = C + (size_t)row * N + col;
            #pragma unroll
            for (int r = 0; r < 4; ++r)
                cp[(size_t)r * N] = acc[mi][ni][r];
        }
    }
}

extern "C" void kernel_launch(void* const* d_in, const int* in_sizes, int n_in,
                              void* d_out, int out_size, void* d_ws, size_t ws_size,
                              hipStream_t stream) {
    const float* x = (const float*)d_in[0];
    const float* w = (const float*)d_in[1];
    float* out = (float*)d_out;

    const int K = 4096;
    const int T = in_sizes[0] / K;   // 8192
    const int O = in_sizes[1] / K;   // 4096

    uint16_t* xq = (uint16_t*)d_ws;                                  // T*K bf16
    uint16_t* wq = (uint16_t*)((char*)d_ws + (size_t)T * K * 2);     // O*K bf16

    quant_kernel<<<2048, 256, 0, stream>>>(x, xq, (T * K) >> 2);
    quant_kernel<<<2048, 256, 0, stream>>>(w, wq, (O * K) >> 2);

    int nwg = (T / BM) * (O / BN);   // 32*16 = 512
    gemm_kernel<<<nwg, 512, 0, stream>>>(xq, wq, out, T, O, K);
}